// Round 9
// baseline (4425.091 us; speedup 1.0000x reference)
//
#include <hip/hip_runtime.h>

#define N_NEUR 4096
#define B_SZ   64
#define T_STEPS 128
#define N_CLS  10

typedef double d4v __attribute__((ext_vector_type(4)));
typedef int    i4v __attribute__((ext_vector_type(4)));
typedef long   l2v __attribute__((ext_vector_type(2)));

// =====================================================================================
// i8 3-digit fixed-point persistent path (GEMM/reduce/LIF verified r8). This round:
//  - TAG-SYNC: mask words carry step number in high 16 bits; polling the data IS the
//    barrier (no bar atomics, no leader spin, one fewer L3 round trip per step)
//  - Wout segment pinned in LDS (kills r8's 13.8 MB/step FETCH regression)
//  - 4 syncthreads/step, zero global-barrier ops
// Safety: block writes tag-t mask only after reading ALL tag-(t-1) words => write skew
// <= 1 step => double buffering safe. P-pipeline ordered by syncthreads' implicit
// vmcnt(0) drain before the tagged store.
// =====================================================================================

__device__ inline int korder2(int map, int khi, int e) {
    return map ? ((khi << 3) | e)
               : (((e >> 2) << 4) | (khi << 2) | (e & 3));
}

// ---------------- layout probe for i8 MFMA: combo[3] = am | bm<<1 | dmap<<2 ----------------
__global__ void kernProbe3(int* __restrict__ combo_out) {
    int l = threadIdx.x;
    int khi = l >> 4, c = l & 15;
    int best = -1;
    for (int cb = 0; cb < 8; ++cb) {
        int am = cb & 1, bm = (cb >> 1) & 1, dmap = (cb >> 2) & 1;
        unsigned long long au = 0, bu = 0;
        #pragma unroll
        for (int e = 0; e < 8; ++e) {
            int ka = korder2(am, khi, e);
            int kb = korder2(bm, khi, e);
            int aval = ((c * 5 + ka * 3) % 51) - 25;
            int bval = ((kb * 7 + c * 13) % 51) - 25;
            au |= (unsigned long long)(unsigned char)(char)aval << (8 * e);
            bu |= (unsigned long long)(unsigned char)(char)bval << (8 * e);
        }
        i4v d = {0, 0, 0, 0};
        d = __builtin_amdgcn_mfma_i32_16x16x32_i8((long)au, (long)bu, d, 0, 0, 0);
        bool ok = true;
        #pragma unroll
        for (int r = 0; r < 4; ++r) {
            int q = (l >> 4) * 4 + r;
            int di = dmap ? c : q;
            int dj = dmap ? q : c;
            int ref = 0;
            for (int k = 0; k < 32; ++k)
                ref += (((di * 5 + k * 3) % 51) - 25) * (((k * 7 + dj * 13) % 51) - 25);
            ok = ok && (d[r] == ref);
        }
        unsigned long long m = __ballot(ok);
        if (m == ~0ull && best < 0) best = cb;
    }
    if (l == 0) combo_out[3] = (best < 0) ? 0 : best;
}

// ---------------- global max|W| then scale exponent ----------------
__global__ __launch_bounds__(256) void kernS(const float* __restrict__ W, unsigned* __restrict__ mx) {
    unsigned m = 0;
    for (size_t i = (size_t)blockIdx.x * blockDim.x + threadIdx.x;
         i < (size_t)N_NEUR * N_NEUR; i += (size_t)gridDim.x * blockDim.x)
        m = max(m, __float_as_uint(fabsf(W[i])));
    for (int off = 32; off > 0; off >>= 1)
        m = max(m, (unsigned)__shfl_down((int)m, off, 64));
    if ((threadIdx.x & 63) == 0) atomicMax(mx, m);
}

__global__ void kernSc(const unsigned* __restrict__ mx, int* __restrict__ combo) {
    float m = __uint_as_float(*mx);
    int s = 26;
    if (m > 1e-30f) {
        s = (int)floorf(log2f(8.3e6f / m));
        while (ldexpf(m, s) > 8.3e6f) --s;
        while (ldexpf(m, s + 1) <= 8.3e6f) ++s;
    }
    combo[2] = s;
}

// ---------------- pack W into 3 i8 digit planes, A-fragment order (verified r4-r8) ----------------
__global__ __launch_bounds__(256) void kernP3(const float* __restrict__ W,
                                              char* __restrict__ Wf,
                                              const int* __restrict__ combo_p) {
    const int am = combo_p[3] & 1;
    const int sc = combo_p[2];
    const int nt = blockIdx.x;
    const int lane = threadIdx.x & 63, wv = threadIdx.x >> 6;
    const int khi = lane >> 4, ai = lane & 15;
    const float* wrow = W + (size_t)(nt * 16 + ai) * N_NEUR;
    for (int kt = wv; kt < 64; kt += 4) {
        unsigned long long p0[2] = {0, 0}, p1[2] = {0, 0}, p2[2] = {0, 0};
        #pragma unroll
        for (int half = 0; half < 2; ++half) {
            #pragma unroll
            for (int e = 0; e < 8; ++e) {
                int kk = kt * 64 + half * 32 + korder2(am, khi, e);
                float w = wrow[kk];
                int q = (int)rintf(ldexpf(w, sc));
                int b0 = (int)(char)(q & 255);  int r1 = (q - b0) >> 8;
                int b1 = (int)(char)(r1 & 255); int b2 = (r1 - b1) >> 8;
                p0[half] |= (unsigned long long)(unsigned char)(char)b0 << (8 * e);
                p1[half] |= (unsigned long long)(unsigned char)(char)b1 << (8 * e);
                p2[half] |= (unsigned long long)(unsigned char)(char)b2 << (8 * e);
            }
        }
        size_t base = (((size_t)nt * 64 + kt) * 3) * 1024 + (size_t)lane * 16;
        *(l2v*)(Wf + base)        = (l2v){(long)p0[0], (long)p0[1]};
        *(l2v*)(Wf + base + 1024) = (l2v){(long)p1[0], (long)p1[1]};
        *(l2v*)(Wf + base + 2048) = (l2v){(long)p2[0], (long)p2[1]};
    }
}

// ---------------- t=0 init: vr + spike bitmask (tag 0 = memset high bits) ----------------
__global__ __launch_bounds__(256) void kernI3m(const float* __restrict__ x,
                                               const float* __restrict__ Win,
                                               double* __restrict__ vr,
                                               unsigned* __restrict__ m0) {
    int idx = blockIdx.x * 256 + threadIdx.x;
    int b = idx & 63, n = idx >> 6;
    double v = (double)x[b * T_STEPS] * (double)Win[n];
    bool sp = (v >= 1.0);
    vr[idx] = sp ? 0.0 : v;
    if (sp)
        __hip_atomic_fetch_or(&m0[b * 256 + (n >> 4)], 1u << (n & 15),
                              __ATOMIC_RELAXED, __HIP_MEMORY_SCOPE_AGENT);
}

// bit(e) of byte8 -> byte e value {0,1}  (carry-free multiply spread, verified r7/r8)
__device__ __forceinline__ unsigned long long expand8(unsigned w, int khi, int bm) {
    unsigned byte8;
    if (bm) byte8 = (w >> (khi * 8)) & 0xFFu;
    else    byte8 = ((w >> (khi * 4)) & 0xFu) | (((w >> (16 + khi * 4)) & 0xFu) << 4);
    unsigned rev = __builtin_bitreverse32(byte8) >> 24;
    return (((unsigned long long)rev * 0x8040201008040201ULL)
            & 0x8080808080808080ULL) >> 7;
}

// ---------------- persistent tag-sync loop: 256 blocks x 1024 threads, NO grid barrier ----------------
__global__ __launch_bounds__(1024) void kernLoop8(const char* __restrict__ Wf,
                                                  unsigned* __restrict__ m0,
                                                  unsigned* __restrict__ m1,
                                                  const float* __restrict__ x,
                                                  const float* __restrict__ Win,
                                                  double* __restrict__ vr,
                                                  const float* __restrict__ Wout,
                                                  double* __restrict__ vc,
                                                  double* __restrict__ counts,
                                                  double* __restrict__ P0,
                                                  double* __restrict__ P1,
                                                  const int* __restrict__ combo_p) {
    __shared__ int2 lbufI[8][1024];           // 64 KB  exact i32-packed cross-wave reduce
    __shared__ unsigned Lm[128 * 65];         // 33 KB  combined mask words [jw][b] (pad 65)
    __shared__ float Wlds[N_CLS * 1024];      // 40 KB  Wout segment, resident
    __shared__ unsigned char spk[1024];       //  1 KB  spike bits staging
    const int bid = blockIdx.x, tid = threadIdx.x;
    const int wave = tid >> 6, lane = tid & 63;
    const int comboI = combo_p[3];
    const int sc = combo_p[2];
    const int bm = (comboI >> 1) & 1, dmap = (comboI >> 2) & 1;
    const double inv = ldexp(1.0, -sc);
    const int khi = lane >> 4, c = lane & 15;

    // resident A: 12 fragments
    l2v aR[12];
    {
        const char* ap = Wf + (((size_t)bid * 64 + (size_t)wave * 4) * 3) * 1024 + (size_t)lane * 16;
        #pragma unroll
        for (int f = 0; f < 12; ++f)
            aR[f] = *(const l2v*)(ap + f * 1024);
    }

    const int nn = bid * 16 + wave;
    const int bb = lane;
    const size_t gidx = (size_t)nn * 64 + bb;
    const double winv = (double)Win[nn];
    const int b2 = bid >> 2;
    const int mbase = (bid & 3) << 10;        // classifier m-range base

    // preload Wout segment into LDS (first iteration's syncthreads covers visibility)
    #pragma unroll
    for (int r = 0; r < N_CLS; ++r)
        Wlds[r * 1024 + tid] = Wout[r * N_NEUR + mbase + tid];

    for (int t = 1; t < T_STEPS; ++t) {
        const unsigned* mp = (t & 1) ? m0 : m1;
        unsigned*       mc = (t & 1) ? m1 : m0;
        double* Pcur  = (t & 1) ? P1 : P0;
        double* Pprev = (t & 1) ? P0 : P1;
        const unsigned long long tg = (unsigned long long)(unsigned)(t - 1);

        // ---- tagged poll-copy: the data load IS the barrier ----
        {
            const unsigned long long* mp64 = (const unsigned long long*)mp;
            unsigned long long vv[8];
            #pragma unroll
            for (int r = 0; r < 8; ++r)
                vv[r] = __hip_atomic_load(&mp64[r * 1024 + tid], __ATOMIC_RELAXED,
                                          __HIP_MEMORY_SCOPE_AGENT);
            #pragma unroll
            for (int r = 0; r < 8; ++r) {
                while ((((vv[r] >> 16) & 0xFFFFull) != tg) || ((vv[r] >> 48) != tg)) {
                    __builtin_amdgcn_s_sleep(1);
                    vv[r] = __hip_atomic_load(&mp64[r * 1024 + tid], __ATOMIC_RELAXED,
                                              __HIP_MEMORY_SCOPE_AGENT);
                }
                int idx2 = r * 1024 + tid;
                int b = idx2 >> 7, jw = idx2 & 127;
                Lm[jw * 65 + b] = (unsigned)(vv[r] & 0xFFFFu)
                                | ((unsigned)((vv[r] >> 32) & 0xFFFFu) << 16);
            }
        }
        double xin = (double)x[bb * T_STEPS + t] * winv;
        double vprev = vr[gidx];                           // block-private, cached
        __syncthreads();                                   // S1: Lm (+Wlds, t=1) ready

        // ---- GEMM: single pass, 4 b-tiles, bit-expanded B from LDS (verified r8) ----
        i4v acc[4][3];
        #pragma unroll
        for (int i = 0; i < 4; ++i)
            #pragma unroll
            for (int s = 0; s < 3; ++s)
                acc[i][s] = (i4v){0, 0, 0, 0};
        #pragma unroll
        for (int kt = 0; kt < 4; ++kt) {
            int ktg = wave * 4 + kt;
            #pragma unroll
            for (int bl = 0; bl < 4; ++bl) {
                int bcol = bl * 16 + c;
                unsigned w0 = Lm[(ktg * 2 + 0) * 65 + bcol];
                unsigned w1 = Lm[(ktg * 2 + 1) * 65 + bcol];
                long lo = (long)expand8(w0, khi, bm);
                long hi = (long)expand8(w1, khi, bm);
                #pragma unroll
                for (int s = 0; s < 3; ++s) {
                    acc[bl][s] = __builtin_amdgcn_mfma_i32_16x16x32_i8(aR[kt * 3 + s][0], lo, acc[bl][s], 0, 0, 0);
                    acc[bl][s] = __builtin_amdgcn_mfma_i32_16x16x32_i8(aR[kt * 3 + s][1], hi, acc[bl][s], 0, 0, 0);
                }
            }
        }

        // ---- classifier: wave-per-class, Wout from LDS (no global traffic) ----
        double ctot = 0.0;
        if (wave < N_CLS) {
            double s = 0.0;
            #pragma unroll
            for (int j = 0; j < 16; ++j) {
                unsigned wd = Lm[((mbase >> 5) + j * 2 + (lane >> 5)) * 65 + b2];
                if ((wd >> (lane & 31)) & 1u)
                    s += (double)Wlds[wave * 1024 + j * 64 + lane];
            }
            for (int off = 32; off > 0; off >>= 1)
                s += __shfl_down(s, off, 64);
            ctot = s;                                      // valid on lane 0
        }

        // ---- exact i32-packed recombine + two-phase 16->8 cross-wave reduce (r8) ----
        {
            int2 pk[4][4];
            int ix[4][4];
            #pragma unroll
            for (int bl = 0; bl < 4; ++bl) {
                #pragma unroll
                for (int r = 0; r < 4; ++r) {
                    pk[bl][r].x = acc[bl][0][r] + acc[bl][1][r] * 256;   // 16-wave sum < 2^31
                    pk[bl][r].y = acc[bl][2][r];
                    int q = (lane >> 4) * 4 + r;
                    int di = dmap ? (lane & 15) : q;
                    int dj = dmap ? q : (lane & 15);
                    ix[bl][r] = di * 64 + bl * 16 + dj;
                }
            }
            if (wave < 8) {
                #pragma unroll
                for (int bl = 0; bl < 4; ++bl)
                    #pragma unroll
                    for (int r = 0; r < 4; ++r)
                        lbufI[wave][ix[bl][r]] = pk[bl][r];
            }
            __syncthreads();                               // S2
            if (wave >= 8) {
                #pragma unroll
                for (int bl = 0; bl < 4; ++bl)
                    #pragma unroll
                    for (int r = 0; r < 4; ++r) {
                        int2 tcur = lbufI[wave - 8][ix[bl][r]];
                        tcur.x += pk[bl][r].x;
                        tcur.y += pk[bl][r].y;
                        lbufI[wave - 8][ix[bl][r]] = tcur;
                    }
            }
            __syncthreads();                               // S3
        }

        // ---- reservoir LIF (one output per thread; single exact recombine) ----
        {
            int s01 = 0, s2 = 0;
            #pragma unroll
            for (int j = 0; j < 8; ++j) {
                int2 v2 = lbufI[j][tid];
                s01 += v2.x;
                s2  += v2.y;
            }
            double cur = inv * ((double)s01 + 65536.0 * (double)s2) + xin;
            double v = 0.9 * vprev + cur;
            bool sp = (v >= 1.0);
            vr[gidx] = sp ? 0.0 : v;
            spk[lane * 16 + wave] = sp ? 1 : 0;            // [b][n-local]
        }

        // classifier commit (P-add; drained to L3 by S4's implicit vmcnt(0))
        if (wave < N_CLS && lane == 0)
            atomicAdd(&Pcur[b2 * N_CLS + wave], ctot);

        __syncthreads();                                   // S4: spk ready + P-adds drained

        // ---- wave 0: classifier LIF for s_{t-2}, then TAGGED mask store (the "arrive") ----
        if (wave == 0) {
            unsigned v16 = 0;
            #pragma unroll
            for (int i = 0; i < 16; ++i) v16 |= (unsigned)spk[lane * 16 + i] << i;
            if (lane < N_CLS && bid < B_SZ && t >= 2) {
                double pv = __hip_atomic_load(&Pprev[bid * N_CLS + lane],
                                              __ATOMIC_RELAXED, __HIP_MEMORY_SCOPE_AGENT);
                double v = 0.9 * vc[bid * N_CLS + lane] + pv;
                bool sp = (v >= 1.0);
                vc[bid * N_CLS + lane] = sp ? 0.0 : v;
                if (sp) counts[bid * N_CLS + lane] += 1.0;
                __hip_atomic_store(&Pprev[bid * N_CLS + lane], 0.0,
                                   __ATOMIC_RELAXED, __HIP_MEMORY_SCOPE_AGENT);
            }
            asm volatile("s_waitcnt vmcnt(0)" ::: "memory");   // P-zero complete before tag
            __hip_atomic_store(&mc[lane * 256 + bid],
                               ((unsigned)t << 16) | v16,
                               __ATOMIC_RELAXED, __HIP_MEMORY_SCOPE_AGENT);
        }
        // no end barrier: next iteration's S1 protects Lm; spk protected by S1 ordering
    }
}

// ---------------- epilogue: vc for s_126 (from P1) then s_127 (mask dot; tags in high bits) ----------------
__global__ __launch_bounds__(256) void kernC2m(const unsigned* __restrict__ m1,
                                               const float* __restrict__ Wout,
                                               double* __restrict__ vc,
                                               double* __restrict__ counts,
                                               const double* __restrict__ Pp) {
    int b = blockIdx.x;
    int tid = threadIdx.x;
    if (tid < N_CLS) {
        double v = 0.9 * vc[b * N_CLS + tid] + Pp[b * N_CLS + tid];
        bool sp = (v >= 1.0);
        vc[b * N_CLS + tid] = sp ? 0.0 : v;
        if (sp) counts[b * N_CLS + tid] += 1.0;
    }
    double part[N_CLS];
    #pragma unroll
    for (int c = 0; c < N_CLS; ++c) part[c] = 0.0;
    for (int m = tid; m < N_NEUR; m += 256) {
        unsigned w = m1[b * 256 + (m >> 4)];
        if ((w >> (m & 15)) & 1u) {                        // low-16 payload only
            #pragma unroll
            for (int c = 0; c < N_CLS; ++c)
                part[c] += (double)Wout[c * N_NEUR + m];
        }
    }
    __shared__ double red[4][N_CLS];
    int lane = tid & 63, wv = tid >> 6;
    #pragma unroll
    for (int c = 0; c < N_CLS; ++c) {
        double v = part[c];
        for (int off = 32; off > 0; off >>= 1)
            v += __shfl_down(v, off, 64);
        if (lane == 0) red[wv][c] = v;
    }
    __syncthreads();
    if (tid < N_CLS) {
        double tot = red[0][tid] + red[1][tid] + red[2][tid] + red[3][tid];
        double v = 0.9 * vc[b * N_CLS + tid] + tot;
        bool sp = (v >= 1.0);
        vc[b * N_CLS + tid] = sp ? 0.0 : v;
        if (sp) counts[b * N_CLS + tid] += 1.0;
    }
}

__global__ void kernD(const double* __restrict__ counts, float* __restrict__ out) {
    int i = blockIdx.x * blockDim.x + threadIdx.x;
    if (i < B_SZ * N_CLS) out[i] = (float)counts[i];
}

// =====================================================================================
// f64 fallback path (verified) — used when ws too small for the i8 planes.
// =====================================================================================

__global__ void kernProbe(int* __restrict__ combo_out) {
    int l = threadIdx.x;
    int best = -1;
    for (int c = 0; c < 16; ++c) {
        int amap = c & 1, bmap = (c >> 1) & 1, dmap = (c >> 2) & 3;
        int ai = amap ? (l >> 2) : (l & 15);
        int ak = amap ? (l & 3)  : (l >> 4);
        int bk = bmap ? (l & 3)  : (l >> 4);
        int bj = bmap ? (l >> 2) : (l & 15);
        double a = (double)(ai * 4 + ak + 1);
        double b = (double)(bk * 16 + bj + 1);
        d4v d = {0.0, 0.0, 0.0, 0.0};
        d = __builtin_amdgcn_mfma_f64_16x16x4f64(a, b, d, 0, 0, 0);
        bool ok = true;
        #pragma unroll
        for (int r = 0; r < 4; ++r) {
            int di, dj;
            if      (dmap == 0) { di = 4 * (l >> 4) + r; dj = l & 15; }
            else if (dmap == 1) { di = l & 15; dj = 4 * (l >> 4) + r; }
            else if (dmap == 2) { di = (l >> 4) + 4 * r; dj = l & 15; }
            else                { di = l & 15; dj = (l >> 4) + 4 * r; }
            double ref = 0.0;
            for (int k = 0; k < 4; ++k)
                ref += (double)(di * 4 + k + 1) * (double)(k * 16 + dj + 1);
            ok = ok && (d[r] == ref);
        }
        unsigned long long m = __ballot(ok);
        if (m == ~0ull && best < 0) best = c;
    }
    if (l == 0) combo_out[0] = (best < 0) ? 0 : best;
}

__global__ __launch_bounds__(256) void kernP(const float* __restrict__ W,
                                             float* __restrict__ Wf,
                                             const int* __restrict__ combo_p) {
    const int combo = combo_p[0];
    const int amap = combo & 1;
    const int stripe = blockIdx.x;
    const int lane = threadIdx.x & 63;
    const int ai = amap ? (lane >> 2) : (lane & 15);
    const int ak = amap ? (lane & 3)  : (lane >> 4);
    const size_t nrow = (size_t)(stripe * 16 + ai) * N_NEUR;
    for (int q = threadIdx.x >> 6; q < 1024; q += 4)
        Wf[((size_t)stripe * 1024 + q) * 64 + lane] = W[nrow + 4 * q + ak];
}

__global__ __launch_bounds__(256) void kernI(const float* __restrict__ x,
                                             const float* __restrict__ Win,
                                             double* __restrict__ vr,
                                             float* __restrict__ sf,
                                             float* __restrict__ sT) {
    int idx = blockIdx.x * 256 + threadIdx.x;
    int b = idx & 63, n = idx >> 6;
    double v = (double)x[b * T_STEPS] * (double)Win[n];
    bool sp = (v >= 1.0);
    vr[idx] = sp ? 0.0 : v;
    float s = sp ? 1.0f : 0.0f;
    sT[idx] = s;
    sf[(size_t)(((n >> 2) * 4 + (b >> 4)) * 64) + (n & 3) * 16 + (b & 15)] = s;
}

template<bool USEWF>
__global__ __launch_bounds__(1024) void kernAB(const float* __restrict__ Wsrc,
                                               const float* __restrict__ sfp,
                                               const float* __restrict__ x,
                                               const float* __restrict__ Win,
                                               double* __restrict__ vr,
                                               float* __restrict__ sfc,
                                               float* __restrict__ sTc,
                                               const float* __restrict__ sTp,
                                               const float* __restrict__ Wout,
                                               double* __restrict__ vc,
                                               double* __restrict__ counts,
                                               const int* __restrict__ combo_p,
                                               int t) {
    __shared__ double lbuf[4][16 * 64];
    __shared__ double red[16][N_CLS];
    const int tid  = threadIdx.x;
    const int wave = tid >> 6, lane = tid & 63;

    if (blockIdx.x >= 256) {
        const int b = blockIdx.x - 256;
        double part[N_CLS];
        #pragma unroll
        for (int c = 0; c < N_CLS; ++c) part[c] = 0.0;
        for (int m = tid; m < N_NEUR; m += 1024) {
            double s = (double)sTp[(size_t)m * B_SZ + b];
            #pragma unroll
            for (int c = 0; c < N_CLS; ++c)
                part[c] = fma(s, (double)Wout[c * N_NEUR + m], part[c]);
        }
        #pragma unroll
        for (int c = 0; c < N_CLS; ++c) {
            double v = part[c];
            for (int off = 32; off > 0; off >>= 1)
                v += __shfl_down(v, off, 64);
            if (lane == 0) red[wave][c] = v;
        }
        __syncthreads();
        if (tid < N_CLS) {
            double tot = 0.0;
            #pragma unroll
            for (int wv = 0; wv < 16; ++wv) tot += red[wv][tid];
            double v = 0.9 * vc[b * N_CLS + tid] + tot;
            bool sp = (v >= 1.0);
            vc[b * N_CLS + tid] = sp ? 0.0 : v;
            if (sp) counts[b * N_CLS + tid] += 1.0;
        }
        return;
    }

    const int wb = wave & 3, wq = wave >> 2;
    const int gn0 = blockIdx.x * 16;
    const int combo = combo_p[0];
    const int amap = combo & 1, bmap = (combo >> 1) & 1, dmap = (combo >> 2) & 3;
    const int bk = bmap ? (lane & 3)  : (lane >> 4);
    const int bj = bmap ? (lane >> 2) : (lane & 15);

    d4v acc = {0.0, 0.0, 0.0, 0.0};
    const int q0 = wq * 256;
    const float* bp = sfp + (size_t)(q0 * 4 + wb) * 64 + bk * 16 + bj;

    if (USEWF) {
        const float* ap = Wsrc + ((size_t)blockIdx.x * 1024 + q0) * 64 + lane;
        for (int blk = 0; blk < 64; ++blk) {
            #pragma unroll
            for (int u = 0; u < 4; ++u) {
                double a  = (double)ap[u * 64];
                double bv = (double)bp[u * 256];
                acc = __builtin_amdgcn_mfma_f64_16x16x4f64(a, bv, acc, 0, 0, 0);
            }
            ap += 256;
            bp += 1024;
        }
    } else {
        const int ai = amap ? (lane >> 2) : (lane & 15);
        const int ak = amap ? (lane & 3)  : (lane >> 4);
        #pragma unroll 4
        for (int q = 0; q < 256; ++q) {
            double a  = (double)Wsrc[(size_t)(gn0 + ai) * N_NEUR + 4 * (q0 + q) + ak];
            double bv = (double)bp[(size_t)q * 256];
            acc = __builtin_amdgcn_mfma_f64_16x16x4f64(a, bv, acc, 0, 0, 0);
        }
    }

    {
        const int jb = 16 * wb;
        #pragma unroll
        for (int r = 0; r < 4; ++r) {
            int di, dj;
            if      (dmap == 0) { di = 4 * (lane >> 4) + r; dj = lane & 15; }
            else if (dmap == 1) { di = lane & 15; dj = 4 * (lane >> 4) + r; }
            else if (dmap == 2) { di = (lane >> 4) + 4 * r; dj = lane & 15; }
            else                { di = lane & 15; dj = (lane >> 4) + 4 * r; }
            lbuf[wq][di * 64 + jb + dj] = acc[r];
        }
    }
    __syncthreads();

    int nl = tid >> 6, b = tid & 63;
    int n = gn0 + nl;
    size_t gidx = (size_t)n * 64 + b;
    double cur = lbuf[0][tid] + lbuf[1][tid] + lbuf[2][tid] + lbuf[3][tid]
               + (double)x[b * T_STEPS + t] * (double)Win[n];
    double v = 0.9 * vr[gidx] + cur;
    bool sp = (v >= 1.0);
    vr[gidx] = sp ? 0.0 : v;
    float s = sp ? 1.0f : 0.0f;
    sTc[gidx] = s;
    sfc[(size_t)(((n >> 2) * 4 + (b >> 4)) * 64) + (n & 3) * 16 + (b & 15)] = s;
}

__global__ __launch_bounds__(256) void kernC(const float* __restrict__ sT,
                                             const float* __restrict__ Wout,
                                             double* __restrict__ vc,
                                             double* __restrict__ counts) {
    int b = blockIdx.x;
    int tid = threadIdx.x;
    double part[N_CLS];
    #pragma unroll
    for (int c = 0; c < N_CLS; ++c) part[c] = 0.0;
    for (int m = tid; m < N_NEUR; m += 256) {
        double s = (double)sT[(size_t)m * B_SZ + b];
        #pragma unroll
        for (int c = 0; c < N_CLS; ++c)
            part[c] = fma(s, (double)Wout[c * N_NEUR + m], part[c]);
    }
    __shared__ double red[4][N_CLS];
    int lane = tid & 63, wv = tid >> 6;
    #pragma unroll
    for (int c = 0; c < N_CLS; ++c) {
        double v = part[c];
        for (int off = 32; off > 0; off >>= 1)
            v += __shfl_down(v, off, 64);
        if (lane == 0) red[wv][c] = v;
    }
    __syncthreads();
    if (tid < N_CLS) {
        double tot = red[0][tid] + red[1][tid] + red[2][tid] + red[3][tid];
        double v = 0.9 * vc[b * N_CLS + tid] + tot;
        bool sp = (v >= 1.0);
        vc[b * N_CLS + tid] = sp ? 0.0 : v;
        if (sp) counts[b * N_CLS + tid] += 1.0;
    }
}

extern "C" void kernel_launch(void* const* d_in, const int* in_sizes, int n_in,
                              void* d_out, int out_size, void* d_ws, size_t ws_size,
                              hipStream_t stream) {
    const float* x    = (const float*)d_in[0];
    const float* Win  = (const float*)d_in[1];
    const float* Wres = (const float*)d_in[2];
    const float* Wout = (const float*)d_in[3];
    float* out = (float*)d_out;

    const size_t NB = (size_t)B_SZ * N_NEUR;
    char* w = (char*)d_ws;
    double* vr     = (double*)w;  w += NB * sizeof(double);
    float*  sTa    = (float*)w;   w += NB * sizeof(float);
    float*  sTb    = (float*)w;   w += NB * sizeof(float);
    float*  sf0    = (float*)w;   w += NB * sizeof(float);   // i8 path: tagged mask m0
    float*  sf1    = (float*)w;   w += NB * sizeof(float);   // i8 path: tagged mask m1
    double* vc     = (double*)w;  w += (size_t)B_SZ * N_CLS * sizeof(double);
    double* counts = (double*)w;  w += (size_t)B_SZ * N_CLS * sizeof(double);
    double* P0     = (double*)w;  w += (size_t)B_SZ * N_CLS * sizeof(double);
    double* P1     = (double*)w;  w += (size_t)B_SZ * N_CLS * sizeof(double);
    int*    combo  = (int*)w;     w += 256;
    unsigned* bar  = (unsigned*)w; w += 4096;                // unused this round (layout compat)
    float*  Wf     = (float*)w;   // f64 path: 64 MB packed W; i8 path: 48 MB digit planes

    size_t fixed = (size_t)(w - (char*)d_ws);
    bool use_i8 = (ws_size >= fixed + 3ull * N_NEUR * N_NEUR);
    bool use_wf = (ws_size >= fixed + (size_t)N_NEUR * N_NEUR * sizeof(float));

    hipMemsetAsync(vc, 0, 4ull * B_SZ * N_CLS * sizeof(double), stream);   // vc, counts, P0, P1
    hipMemsetAsync(combo, 0, 256, stream);
    hipMemsetAsync(bar, 0, 4096, stream);

    if (use_i8) {
        char* Wfi = (char*)Wf;
        unsigned* m0 = (unsigned*)sf0;
        unsigned* m1 = (unsigned*)sf1;
        unsigned* mx = (unsigned*)(combo + 8);

        hipMemsetAsync(m0, 0, 64 * 1024, stream);
        hipMemsetAsync(m1, 0, 64 * 1024, stream);

        kernProbe3<<<dim3(1), 64, 0, stream>>>(combo);
        kernS<<<dim3(1024), 256, 0, stream>>>(Wres, mx);
        kernSc<<<dim3(1), 1, 0, stream>>>(mx, combo);
        kernP3<<<dim3(256), 256, 0, stream>>>(Wres, Wfi, combo);
        kernI3m<<<dim3(NB / 256), 256, 0, stream>>>(x, Win, vr, m0);

        kernLoop8<<<dim3(256), 1024, 0, stream>>>(Wfi, m0, m1, x, Win, vr,
                                                  Wout, vc, counts, P0, P1, combo);

        kernC2m<<<dim3(B_SZ), 256, 0, stream>>>(m1, Wout, vc, counts, P1);
        kernD<<<dim3(3), 256, 0, stream>>>(counts, out);
        return;
    }

    kernProbe<<<dim3(1), 64, 0, stream>>>(combo);
    if (use_wf)
        kernP<<<dim3(256), 256, 0, stream>>>(Wres, Wf, combo);

    kernI<<<dim3(NB / 256), 256, 0, stream>>>(x, Win, vr, sf0, sTa);
    for (int t = 1; t < T_STEPS; ++t) {
        const float* sfp = (t & 1) ? sf0 : sf1;
        float*       sfc = (t & 1) ? sf1 : sf0;
        float*       sTc = (t & 1) ? sTb : sTa;
        const float* sTp = (t & 1) ? sTa : sTb;
        if (use_wf)
            kernAB<true><<<dim3(320), 1024, 0, stream>>>(Wf, sfp, x, Win, vr, sfc, sTc, sTp,
                                                         Wout, vc, counts, combo, t);
        else
            kernAB<false><<<dim3(320), 1024, 0, stream>>>(Wres, sfp, x, Win, vr, sfc, sTc, sTp,
                                                          Wout, vc, counts, combo, t);
    }
    kernC<<<dim3(B_SZ), 256, 0, stream>>>(sTb, Wout, vc, counts);
    kernD<<<dim3(3), 256, 0, stream>>>(counts, out);
}

// Round 10
// 3080.317 us; speedup vs baseline: 1.4366x; 1.4366x over previous
//
#include <hip/hip_runtime.h>

#define N_NEUR 4096
#define B_SZ   64
#define T_STEPS 128
#define N_CLS  10

typedef double d4v __attribute__((ext_vector_type(4)));
typedef int    i4v __attribute__((ext_vector_type(4)));
typedef long   l2v __attribute__((ext_vector_type(2)));

// =====================================================================================
// i8 3-digit fixed-point persistent path. Round 10 = clean composition of verified parts:
//  - r7: fence-free leader barrier + plain bitmask exchange (best sync measured)
//  - r8: single-pass GEMM acc[4][3] + exact i32-packed int2 cross-wave reduce
//  - r9: Wout segment pinned in LDS (classifier reads never touch global)
// LDS: 64 (reduce) + 33 (mask) + 40 (Wout) + 1 (spk) = 137.5 KB; 16 waves/CU.
// =====================================================================================

__device__ inline int korder2(int map, int khi, int e) {
    return map ? ((khi << 3) | e)
               : (((e >> 2) << 4) | (khi << 2) | (e & 3));
}

// ---------------- layout probe for i8 MFMA: combo[3] = am | bm<<1 | dmap<<2 ----------------
__global__ void kernProbe3(int* __restrict__ combo_out) {
    int l = threadIdx.x;
    int khi = l >> 4, c = l & 15;
    int best = -1;
    for (int cb = 0; cb < 8; ++cb) {
        int am = cb & 1, bm = (cb >> 1) & 1, dmap = (cb >> 2) & 1;
        unsigned long long au = 0, bu = 0;
        #pragma unroll
        for (int e = 0; e < 8; ++e) {
            int ka = korder2(am, khi, e);
            int kb = korder2(bm, khi, e);
            int aval = ((c * 5 + ka * 3) % 51) - 25;
            int bval = ((kb * 7 + c * 13) % 51) - 25;
            au |= (unsigned long long)(unsigned char)(char)aval << (8 * e);
            bu |= (unsigned long long)(unsigned char)(char)bval << (8 * e);
        }
        i4v d = {0, 0, 0, 0};
        d = __builtin_amdgcn_mfma_i32_16x16x32_i8((long)au, (long)bu, d, 0, 0, 0);
        bool ok = true;
        #pragma unroll
        for (int r = 0; r < 4; ++r) {
            int q = (l >> 4) * 4 + r;
            int di = dmap ? c : q;
            int dj = dmap ? q : c;
            int ref = 0;
            for (int k = 0; k < 32; ++k)
                ref += (((di * 5 + k * 3) % 51) - 25) * (((k * 7 + dj * 13) % 51) - 25);
            ok = ok && (d[r] == ref);
        }
        unsigned long long m = __ballot(ok);
        if (m == ~0ull && best < 0) best = cb;
    }
    if (l == 0) combo_out[3] = (best < 0) ? 0 : best;
}

// ---------------- global max|W| then scale exponent ----------------
__global__ __launch_bounds__(256) void kernS(const float* __restrict__ W, unsigned* __restrict__ mx) {
    unsigned m = 0;
    for (size_t i = (size_t)blockIdx.x * blockDim.x + threadIdx.x;
         i < (size_t)N_NEUR * N_NEUR; i += (size_t)gridDim.x * blockDim.x)
        m = max(m, __float_as_uint(fabsf(W[i])));
    for (int off = 32; off > 0; off >>= 1)
        m = max(m, (unsigned)__shfl_down((int)m, off, 64));
    if ((threadIdx.x & 63) == 0) atomicMax(mx, m);
}

__global__ void kernSc(const unsigned* __restrict__ mx, int* __restrict__ combo) {
    float m = __uint_as_float(*mx);
    int s = 26;
    if (m > 1e-30f) {
        s = (int)floorf(log2f(8.3e6f / m));
        while (ldexpf(m, s) > 8.3e6f) --s;
        while (ldexpf(m, s + 1) <= 8.3e6f) ++s;
    }
    combo[2] = s;
}

// ---------------- pack W into 3 i8 digit planes, A-fragment order (verified r4-r9) ----------------
__global__ __launch_bounds__(256) void kernP3(const float* __restrict__ W,
                                              char* __restrict__ Wf,
                                              const int* __restrict__ combo_p) {
    const int am = combo_p[3] & 1;
    const int sc = combo_p[2];
    const int nt = blockIdx.x;
    const int lane = threadIdx.x & 63, wv = threadIdx.x >> 6;
    const int khi = lane >> 4, ai = lane & 15;
    const float* wrow = W + (size_t)(nt * 16 + ai) * N_NEUR;
    for (int kt = wv; kt < 64; kt += 4) {
        unsigned long long p0[2] = {0, 0}, p1[2] = {0, 0}, p2[2] = {0, 0};
        #pragma unroll
        for (int half = 0; half < 2; ++half) {
            #pragma unroll
            for (int e = 0; e < 8; ++e) {
                int kk = kt * 64 + half * 32 + korder2(am, khi, e);
                float w = wrow[kk];
                int q = (int)rintf(ldexpf(w, sc));
                int b0 = (int)(char)(q & 255);  int r1 = (q - b0) >> 8;
                int b1 = (int)(char)(r1 & 255); int b2 = (r1 - b1) >> 8;
                p0[half] |= (unsigned long long)(unsigned char)(char)b0 << (8 * e);
                p1[half] |= (unsigned long long)(unsigned char)(char)b1 << (8 * e);
                p2[half] |= (unsigned long long)(unsigned char)(char)b2 << (8 * e);
            }
        }
        size_t base = (((size_t)nt * 64 + kt) * 3) * 1024 + (size_t)lane * 16;
        *(l2v*)(Wf + base)        = (l2v){(long)p0[0], (long)p0[1]};
        *(l2v*)(Wf + base + 1024) = (l2v){(long)p1[0], (long)p1[1]};
        *(l2v*)(Wf + base + 2048) = (l2v){(long)p2[0], (long)p2[1]};
    }
}

// ---------------- t=0 init: vr + spike bitmask ----------------
__global__ __launch_bounds__(256) void kernI3m(const float* __restrict__ x,
                                               const float* __restrict__ Win,
                                               double* __restrict__ vr,
                                               unsigned* __restrict__ m0) {
    int idx = blockIdx.x * 256 + threadIdx.x;
    int b = idx & 63, n = idx >> 6;
    double v = (double)x[b * T_STEPS] * (double)Win[n];
    bool sp = (v >= 1.0);
    vr[idx] = sp ? 0.0 : v;
    if (sp)
        __hip_atomic_fetch_or(&m0[b * 256 + (n >> 4)], 1u << (n & 15),
                              __ATOMIC_RELAXED, __HIP_MEMORY_SCOPE_AGENT);
}

// bit(e) of byte8 -> byte e value {0,1}  (carry-free multiply spread, verified r7-r9)
__device__ __forceinline__ unsigned long long expand8(unsigned w, int khi, int bm) {
    unsigned byte8;
    if (bm) byte8 = (w >> (khi * 8)) & 0xFFu;
    else    byte8 = ((w >> (khi * 4)) & 0xFu) | (((w >> (16 + khi * 4)) & 0xFu) << 4);
    unsigned rev = __builtin_bitreverse32(byte8) >> 24;
    return (((unsigned long long)rev * 0x8040201008040201ULL)
            & 0x8080808080808080ULL) >> 7;
}

// ---------------- persistent loop: 256 blocks x 1024 threads, r7 barrier ----------------
__global__ __launch_bounds__(1024) void kernLoop9(const char* __restrict__ Wf,
                                                  unsigned* __restrict__ m0,
                                                  unsigned* __restrict__ m1,
                                                  const float* __restrict__ x,
                                                  const float* __restrict__ Win,
                                                  double* __restrict__ vr,
                                                  const float* __restrict__ Wout,
                                                  double* __restrict__ vc,
                                                  double* __restrict__ counts,
                                                  double* __restrict__ P0,
                                                  double* __restrict__ P1,
                                                  const int* __restrict__ combo_p,
                                                  unsigned* __restrict__ bar) {
    __shared__ int2 lbufI[8][1024];           // 64 KB  exact i32-packed cross-wave reduce
    __shared__ unsigned Lm[128 * 65];         // 33 KB  combined mask words [jw][b] (pad 65)
    __shared__ float Wlds[N_CLS * 1024];      // 40 KB  Wout segment, resident
    __shared__ unsigned char spk[1024];       //  1 KB  spike bits staging
    const int bid = blockIdx.x, tid = threadIdx.x;
    const int wave = tid >> 6, lane = tid & 63;
    const int comboI = combo_p[3];
    const int sc = combo_p[2];
    const int bm = (comboI >> 1) & 1, dmap = (comboI >> 2) & 1;
    const double inv = ldexp(1.0, -sc);
    const int khi = lane >> 4, c = lane & 15;

    // resident A: 12 fragments
    l2v aR[12];
    {
        const char* ap = Wf + (((size_t)bid * 64 + (size_t)wave * 4) * 3) * 1024 + (size_t)lane * 16;
        #pragma unroll
        for (int f = 0; f < 12; ++f)
            aR[f] = *(const l2v*)(ap + f * 1024);
    }

    const int nn = bid * 16 + wave;
    const int bb = lane;
    const size_t gidx = (size_t)nn * 64 + bb;
    const double winv = (double)Win[nn];
    const int b2 = bid >> 2;
    const int mbase = (bid & 3) << 10;        // classifier m-range base

    // preload Wout segment into LDS (first iteration's S1 covers visibility)
    #pragma unroll
    for (int r = 0; r < N_CLS; ++r)
        Wlds[r * 1024 + tid] = Wout[r * N_NEUR + mbase + tid];

    for (int t = 1; t < T_STEPS; ++t) {
        const unsigned* mp = (t & 1) ? m0 : m1;
        unsigned*       mc = (t & 1) ? m1 : m0;
        double* Pcur  = (t & 1) ? P1 : P0;
        double* Pprev = (t & 1) ? P0 : P1;

        // ---- bulk-copy spike mask -> LDS (coherence-point loads; verified r7) ----
        {
            const unsigned long long* mp64 = (const unsigned long long*)mp;
            #pragma unroll
            for (int r = 0; r < 8; ++r) {
                int idx2 = r * 1024 + tid;                 // [b (idx2>>7)][jw (idx2&127)]
                unsigned long long v = __hip_atomic_load(&mp64[idx2], __ATOMIC_RELAXED,
                                                         __HIP_MEMORY_SCOPE_AGENT);
                int b = idx2 >> 7, jw = idx2 & 127;
                Lm[jw * 65 + b] = (unsigned)(v & 0xFFFFu) | ((unsigned)(v >> 32) << 16);
            }
        }
        double xin = (double)x[bb * T_STEPS + t] * winv;
        double vprev = vr[gidx];                           // block-private, cached
        __syncthreads();                                   // S1: Lm (+Wlds, t=1) ready

        // ---- GEMM: single pass, 4 b-tiles, bit-expanded B from LDS (verified r8) ----
        i4v acc[4][3];
        #pragma unroll
        for (int i = 0; i < 4; ++i)
            #pragma unroll
            for (int s = 0; s < 3; ++s)
                acc[i][s] = (i4v){0, 0, 0, 0};
        #pragma unroll
        for (int kt = 0; kt < 4; ++kt) {
            int ktg = wave * 4 + kt;
            #pragma unroll
            for (int bl = 0; bl < 4; ++bl) {
                int bcol = bl * 16 + c;
                unsigned w0 = Lm[(ktg * 2 + 0) * 65 + bcol];
                unsigned w1 = Lm[(ktg * 2 + 1) * 65 + bcol];
                long lo = (long)expand8(w0, khi, bm);
                long hi = (long)expand8(w1, khi, bm);
                #pragma unroll
                for (int s = 0; s < 3; ++s) {
                    acc[bl][s] = __builtin_amdgcn_mfma_i32_16x16x32_i8(aR[kt * 3 + s][0], lo, acc[bl][s], 0, 0, 0);
                    acc[bl][s] = __builtin_amdgcn_mfma_i32_16x16x32_i8(aR[kt * 3 + s][1], hi, acc[bl][s], 0, 0, 0);
                }
            }
        }

        // ---- classifier: wave-per-class, Wout from LDS (verified r9) ----
        double ctot = 0.0;
        if (wave < N_CLS) {
            double s = 0.0;
            #pragma unroll
            for (int j = 0; j < 16; ++j) {
                unsigned wd = Lm[((mbase >> 5) + j * 2 + (lane >> 5)) * 65 + b2];
                if ((wd >> (lane & 31)) & 1u)
                    s += (double)Wlds[wave * 1024 + j * 64 + lane];
            }
            for (int off = 32; off > 0; off >>= 1)
                s += __shfl_down(s, off, 64);
            ctot = s;                                      // valid on lane 0
        }

        // ---- exact i32-packed recombine + two-phase 16->8 cross-wave reduce (r8) ----
        {
            int2 pk[4][4];
            int ix[4][4];
            #pragma unroll
            for (int bl = 0; bl < 4; ++bl) {
                #pragma unroll
                for (int r = 0; r < 4; ++r) {
                    pk[bl][r].x = acc[bl][0][r] + acc[bl][1][r] * 256;   // 16-wave sum < 2^31
                    pk[bl][r].y = acc[bl][2][r];
                    int q = (lane >> 4) * 4 + r;
                    int di = dmap ? (lane & 15) : q;
                    int dj = dmap ? q : (lane & 15);
                    ix[bl][r] = di * 64 + bl * 16 + dj;
                }
            }
            if (wave < 8) {
                #pragma unroll
                for (int bl = 0; bl < 4; ++bl)
                    #pragma unroll
                    for (int r = 0; r < 4; ++r)
                        lbufI[wave][ix[bl][r]] = pk[bl][r];
            }
            __syncthreads();                               // S2
            if (wave >= 8) {
                #pragma unroll
                for (int bl = 0; bl < 4; ++bl)
                    #pragma unroll
                    for (int r = 0; r < 4; ++r) {
                        int2 tcur = lbufI[wave - 8][ix[bl][r]];
                        tcur.x += pk[bl][r].x;
                        tcur.y += pk[bl][r].y;
                        lbufI[wave - 8][ix[bl][r]] = tcur;
                    }
            }
            __syncthreads();                               // S3
        }

        // ---- reservoir LIF (one output per thread; single exact recombine) ----
        {
            int s01 = 0, s2 = 0;
            #pragma unroll
            for (int j = 0; j < 8; ++j) {
                int2 v2 = lbufI[j][tid];
                s01 += v2.x;
                s2  += v2.y;
            }
            double cur = inv * ((double)s01 + 65536.0 * (double)s2) + xin;
            double v = 0.9 * vprev + cur;
            bool sp = (v >= 1.0);
            vr[gidx] = sp ? 0.0 : v;
            spk[lane * 16 + wave] = sp ? 1 : 0;            // [b][n-local]
        }

        // classifier commit (wave owns its class fully)
        if (wave < N_CLS && lane == 0)
            atomicAdd(&Pcur[b2 * N_CLS + wave], ctot);

        __syncthreads();                                   // S4: spk ready

        // ---- wave 0 only: mask store + classifier LIF for s_{t-2} (verified r7) ----
        if (wave == 0) {
            unsigned v16 = 0;
            #pragma unroll
            for (int i = 0; i < 16; ++i) v16 |= (unsigned)spk[lane * 16 + i] << i;
            __hip_atomic_store(&mc[lane * 256 + bid], v16,
                               __ATOMIC_RELAXED, __HIP_MEMORY_SCOPE_AGENT);
            if (lane < N_CLS && bid < B_SZ && t >= 2) {
                double pv = __hip_atomic_load(&Pprev[bid * N_CLS + lane],
                                              __ATOMIC_RELAXED, __HIP_MEMORY_SCOPE_AGENT);
                double v = 0.9 * vc[bid * N_CLS + lane] + pv;
                bool sp = (v >= 1.0);
                vc[bid * N_CLS + lane] = sp ? 0.0 : v;
                if (sp) counts[bid * N_CLS + lane] += 1.0;
                __hip_atomic_store(&Pprev[bid * N_CLS + lane], 0.0,
                                   __ATOMIC_RELAXED, __HIP_MEMORY_SCOPE_AGENT);
            }
        }

        // ---- fence-free monotone grid barrier (verified r7) ----
        __syncthreads();                                   // S5: all waves' vmem drained
        if (tid == 0) {
            asm volatile("s_waitcnt vmcnt(0)" ::: "memory");
            unsigned g = (unsigned)bid >> 4;
            unsigned old = __hip_atomic_fetch_add(&bar[32 + g * 32], 1u,
                                                  __ATOMIC_RELAXED, __HIP_MEMORY_SCOPE_AGENT);
            if ((old & 15u) == 15u)
                __hip_atomic_fetch_add(&bar[0], 1u,
                                       __ATOMIC_RELAXED, __HIP_MEMORY_SCOPE_AGENT);
            unsigned tgt = 16u * (unsigned)t;
            while (__hip_atomic_load(&bar[0], __ATOMIC_RELAXED,
                                     __HIP_MEMORY_SCOPE_AGENT) < tgt)
                __builtin_amdgcn_s_sleep(1);
        }
        __syncthreads();                                   // S6
        asm volatile("" ::: "memory");
    }
}

// ---------------- epilogue: vc for s_126 (from P1) then s_127 (mask dot) ----------------
__global__ __launch_bounds__(256) void kernC2m(const unsigned* __restrict__ m1,
                                               const float* __restrict__ Wout,
                                               double* __restrict__ vc,
                                               double* __restrict__ counts,
                                               const double* __restrict__ Pp) {
    int b = blockIdx.x;
    int tid = threadIdx.x;
    if (tid < N_CLS) {
        double v = 0.9 * vc[b * N_CLS + tid] + Pp[b * N_CLS + tid];
        bool sp = (v >= 1.0);
        vc[b * N_CLS + tid] = sp ? 0.0 : v;
        if (sp) counts[b * N_CLS + tid] += 1.0;
    }
    double part[N_CLS];
    #pragma unroll
    for (int c = 0; c < N_CLS; ++c) part[c] = 0.0;
    for (int m = tid; m < N_NEUR; m += 256) {
        unsigned w = m1[b * 256 + (m >> 4)];
        if ((w >> (m & 15)) & 1u) {
            #pragma unroll
            for (int c = 0; c < N_CLS; ++c)
                part[c] += (double)Wout[c * N_NEUR + m];
        }
    }
    __shared__ double red[4][N_CLS];
    int lane = tid & 63, wv = tid >> 6;
    #pragma unroll
    for (int c = 0; c < N_CLS; ++c) {
        double v = part[c];
        for (int off = 32; off > 0; off >>= 1)
            v += __shfl_down(v, off, 64);
        if (lane == 0) red[wv][c] = v;
    }
    __syncthreads();
    if (tid < N_CLS) {
        double tot = red[0][tid] + red[1][tid] + red[2][tid] + red[3][tid];
        double v = 0.9 * vc[b * N_CLS + tid] + tot;
        bool sp = (v >= 1.0);
        vc[b * N_CLS + tid] = sp ? 0.0 : v;
        if (sp) counts[b * N_CLS + tid] += 1.0;
    }
}

__global__ void kernD(const double* __restrict__ counts, float* __restrict__ out) {
    int i = blockIdx.x * blockDim.x + threadIdx.x;
    if (i < B_SZ * N_CLS) out[i] = (float)counts[i];
}

// =====================================================================================
// f64 fallback path (verified) — used when ws too small for the i8 planes.
// =====================================================================================

__global__ void kernProbe(int* __restrict__ combo_out) {
    int l = threadIdx.x;
    int best = -1;
    for (int c = 0; c < 16; ++c) {
        int amap = c & 1, bmap = (c >> 1) & 1, dmap = (c >> 2) & 3;
        int ai = amap ? (l >> 2) : (l & 15);
        int ak = amap ? (l & 3)  : (l >> 4);
        int bk = bmap ? (l & 3)  : (l >> 4);
        int bj = bmap ? (l >> 2) : (l & 15);
        double a = (double)(ai * 4 + ak + 1);
        double b = (double)(bk * 16 + bj + 1);
        d4v d = {0.0, 0.0, 0.0, 0.0};
        d = __builtin_amdgcn_mfma_f64_16x16x4f64(a, b, d, 0, 0, 0);
        bool ok = true;
        #pragma unroll
        for (int r = 0; r < 4; ++r) {
            int di, dj;
            if      (dmap == 0) { di = 4 * (l >> 4) + r; dj = l & 15; }
            else if (dmap == 1) { di = l & 15; dj = 4 * (l >> 4) + r; }
            else if (dmap == 2) { di = (l >> 4) + 4 * r; dj = l & 15; }
            else                { di = l & 15; dj = (l >> 4) + 4 * r; }
            double ref = 0.0;
            for (int k = 0; k < 4; ++k)
                ref += (double)(di * 4 + k + 1) * (double)(k * 16 + dj + 1);
            ok = ok && (d[r] == ref);
        }
        unsigned long long m = __ballot(ok);
        if (m == ~0ull && best < 0) best = c;
    }
    if (l == 0) combo_out[0] = (best < 0) ? 0 : best;
}

__global__ __launch_bounds__(256) void kernP(const float* __restrict__ W,
                                             float* __restrict__ Wf,
                                             const int* __restrict__ combo_p) {
    const int combo = combo_p[0];
    const int amap = combo & 1;
    const int stripe = blockIdx.x;
    const int lane = threadIdx.x & 63;
    const int ai = amap ? (lane >> 2) : (lane & 15);
    const int ak = amap ? (lane & 3)  : (lane >> 4);
    const size_t nrow = (size_t)(stripe * 16 + ai) * N_NEUR;
    for (int q = threadIdx.x >> 6; q < 1024; q += 4)
        Wf[((size_t)stripe * 1024 + q) * 64 + lane] = W[nrow + 4 * q + ak];
}

__global__ __launch_bounds__(256) void kernI(const float* __restrict__ x,
                                             const float* __restrict__ Win,
                                             double* __restrict__ vr,
                                             float* __restrict__ sf,
                                             float* __restrict__ sT) {
    int idx = blockIdx.x * 256 + threadIdx.x;
    int b = idx & 63, n = idx >> 6;
    double v = (double)x[b * T_STEPS] * (double)Win[n];
    bool sp = (v >= 1.0);
    vr[idx] = sp ? 0.0 : v;
    float s = sp ? 1.0f : 0.0f;
    sT[idx] = s;
    sf[(size_t)(((n >> 2) * 4 + (b >> 4)) * 64) + (n & 3) * 16 + (b & 15)] = s;
}

template<bool USEWF>
__global__ __launch_bounds__(1024) void kernAB(const float* __restrict__ Wsrc,
                                               const float* __restrict__ sfp,
                                               const float* __restrict__ x,
                                               const float* __restrict__ Win,
                                               double* __restrict__ vr,
                                               float* __restrict__ sfc,
                                               float* __restrict__ sTc,
                                               const float* __restrict__ sTp,
                                               const float* __restrict__ Wout,
                                               double* __restrict__ vc,
                                               double* __restrict__ counts,
                                               const int* __restrict__ combo_p,
                                               int t) {
    __shared__ double lbuf[4][16 * 64];
    __shared__ double red[16][N_CLS];
    const int tid  = threadIdx.x;
    const int wave = tid >> 6, lane = tid & 63;

    if (blockIdx.x >= 256) {
        const int b = blockIdx.x - 256;
        double part[N_CLS];
        #pragma unroll
        for (int c = 0; c < N_CLS; ++c) part[c] = 0.0;
        for (int m = tid; m < N_NEUR; m += 1024) {
            double s = (double)sTp[(size_t)m * B_SZ + b];
            #pragma unroll
            for (int c = 0; c < N_CLS; ++c)
                part[c] = fma(s, (double)Wout[c * N_NEUR + m], part[c]);
        }
        #pragma unroll
        for (int c = 0; c < N_CLS; ++c) {
            double v = part[c];
            for (int off = 32; off > 0; off >>= 1)
                v += __shfl_down(v, off, 64);
            if (lane == 0) red[wave][c] = v;
        }
        __syncthreads();
        if (tid < N_CLS) {
            double tot = 0.0;
            #pragma unroll
            for (int wv = 0; wv < 16; ++wv) tot += red[wv][tid];
            double v = 0.9 * vc[b * N_CLS + tid] + tot;
            bool sp = (v >= 1.0);
            vc[b * N_CLS + tid] = sp ? 0.0 : v;
            if (sp) counts[b * N_CLS + tid] += 1.0;
        }
        return;
    }

    const int wb = wave & 3, wq = wave >> 2;
    const int gn0 = blockIdx.x * 16;
    const int combo = combo_p[0];
    const int amap = combo & 1, bmap = (combo >> 1) & 1, dmap = (combo >> 2) & 3;
    const int bk = bmap ? (lane & 3)  : (lane >> 4);
    const int bj = bmap ? (lane >> 2) : (lane & 15);

    d4v acc = {0.0, 0.0, 0.0, 0.0};
    const int q0 = wq * 256;
    const float* bp = sfp + (size_t)(q0 * 4 + wb) * 64 + bk * 16 + bj;

    if (USEWF) {
        const float* ap = Wsrc + ((size_t)blockIdx.x * 1024 + q0) * 64 + lane;
        for (int blk = 0; blk < 64; ++blk) {
            #pragma unroll
            for (int u = 0; u < 4; ++u) {
                double a  = (double)ap[u * 64];
                double bv = (double)bp[u * 256];
                acc = __builtin_amdgcn_mfma_f64_16x16x4f64(a, bv, acc, 0, 0, 0);
            }
            ap += 256;
            bp += 1024;
        }
    } else {
        const int ai = amap ? (lane >> 2) : (lane & 15);
        const int ak = amap ? (lane & 3)  : (lane >> 4);
        #pragma unroll 4
        for (int q = 0; q < 256; ++q) {
            double a  = (double)Wsrc[(size_t)(gn0 + ai) * N_NEUR + 4 * (q0 + q) + ak];
            double bv = (double)bp[(size_t)q * 256];
            acc = __builtin_amdgcn_mfma_f64_16x16x4f64(a, bv, acc, 0, 0, 0);
        }
    }

    {
        const int jb = 16 * wb;
        #pragma unroll
        for (int r = 0; r < 4; ++r) {
            int di, dj;
            if      (dmap == 0) { di = 4 * (lane >> 4) + r; dj = lane & 15; }
            else if (dmap == 1) { di = lane & 15; dj = 4 * (lane >> 4) + r; }
            else if (dmap == 2) { di = (lane >> 4) + 4 * r; dj = lane & 15; }
            else                { di = lane & 15; dj = (lane >> 4) + 4 * r; }
            lbuf[wq][di * 64 + jb + dj] = acc[r];
        }
    }
    __syncthreads();

    int nl = tid >> 6, b = tid & 63;
    int n = gn0 + nl;
    size_t gidx = (size_t)n * 64 + b;
    double cur = lbuf[0][tid] + lbuf[1][tid] + lbuf[2][tid] + lbuf[3][tid]
               + (double)x[b * T_STEPS + t] * (double)Win[n];
    double v = 0.9 * vr[gidx] + cur;
    bool sp = (v >= 1.0);
    vr[gidx] = sp ? 0.0 : v;
    float s = sp ? 1.0f : 0.0f;
    sTc[gidx] = s;
    sfc[(size_t)(((n >> 2) * 4 + (b >> 4)) * 64) + (n & 3) * 16 + (b & 15)] = s;
}

__global__ __launch_bounds__(256) void kernC(const float* __restrict__ sT,
                                             const float* __restrict__ Wout,
                                             double* __restrict__ vc,
                                             double* __restrict__ counts) {
    int b = blockIdx.x;
    int tid = threadIdx.x;
    double part[N_CLS];
    #pragma unroll
    for (int c = 0; c < N_CLS; ++c) part[c] = 0.0;
    for (int m = tid; m < N_NEUR; m += 256) {
        double s = (double)sT[(size_t)m * B_SZ + b];
        #pragma unroll
        for (int c = 0; c < N_CLS; ++c)
            part[c] = fma(s, (double)Wout[c * N_NEUR + m], part[c]);
    }
    __shared__ double red[4][N_CLS];
    int lane = tid & 63, wv = tid >> 6;
    #pragma unroll
    for (int c = 0; c < N_CLS; ++c) {
        double v = part[c];
        for (int off = 32; off > 0; off >>= 1)
            v += __shfl_down(v, off, 64);
        if (lane == 0) red[wv][c] = v;
    }
    __syncthreads();
    if (tid < N_CLS) {
        double tot = red[0][tid] + red[1][tid] + red[2][tid] + red[3][tid];
        double v = 0.9 * vc[b * N_CLS + tid] + tot;
        bool sp = (v >= 1.0);
        vc[b * N_CLS + tid] = sp ? 0.0 : v;
        if (sp) counts[b * N_CLS + tid] += 1.0;
    }
}

extern "C" void kernel_launch(void* const* d_in, const int* in_sizes, int n_in,
                              void* d_out, int out_size, void* d_ws, size_t ws_size,
                              hipStream_t stream) {
    const float* x    = (const float*)d_in[0];
    const float* Win  = (const float*)d_in[1];
    const float* Wres = (const float*)d_in[2];
    const float* Wout = (const float*)d_in[3];
    float* out = (float*)d_out;

    const size_t NB = (size_t)B_SZ * N_NEUR;
    char* w = (char*)d_ws;
    double* vr     = (double*)w;  w += NB * sizeof(double);
    float*  sTa    = (float*)w;   w += NB * sizeof(float);
    float*  sTb    = (float*)w;   w += NB * sizeof(float);
    float*  sf0    = (float*)w;   w += NB * sizeof(float);   // i8 path: mask m0 (64 KB used)
    float*  sf1    = (float*)w;   w += NB * sizeof(float);   // i8 path: mask m1
    double* vc     = (double*)w;  w += (size_t)B_SZ * N_CLS * sizeof(double);
    double* counts = (double*)w;  w += (size_t)B_SZ * N_CLS * sizeof(double);
    double* P0     = (double*)w;  w += (size_t)B_SZ * N_CLS * sizeof(double);
    double* P1     = (double*)w;  w += (size_t)B_SZ * N_CLS * sizeof(double);
    int*    combo  = (int*)w;     w += 256;
    unsigned* bar  = (unsigned*)w; w += 4096;
    float*  Wf     = (float*)w;   // f64 path: 64 MB packed W; i8 path: 48 MB digit planes

    size_t fixed = (size_t)(w - (char*)d_ws);
    bool use_i8 = (ws_size >= fixed + 3ull * N_NEUR * N_NEUR);
    bool use_wf = (ws_size >= fixed + (size_t)N_NEUR * N_NEUR * sizeof(float));

    hipMemsetAsync(vc, 0, 4ull * B_SZ * N_CLS * sizeof(double), stream);   // vc, counts, P0, P1
    hipMemsetAsync(combo, 0, 256, stream);
    hipMemsetAsync(bar, 0, 4096, stream);

    if (use_i8) {
        char* Wfi = (char*)Wf;
        unsigned* m0 = (unsigned*)sf0;
        unsigned* m1 = (unsigned*)sf1;
        unsigned* mx = (unsigned*)(combo + 8);

        hipMemsetAsync(m0, 0, 64 * 1024, stream);
        hipMemsetAsync(m1, 0, 64 * 1024, stream);

        kernProbe3<<<dim3(1), 64, 0, stream>>>(combo);
        kernS<<<dim3(1024), 256, 0, stream>>>(Wres, mx);
        kernSc<<<dim3(1), 1, 0, stream>>>(mx, combo);
        kernP3<<<dim3(256), 256, 0, stream>>>(Wres, Wfi, combo);
        kernI3m<<<dim3(NB / 256), 256, 0, stream>>>(x, Win, vr, m0);

        kernLoop9<<<dim3(256), 1024, 0, stream>>>(Wfi, m0, m1, x, Win, vr,
                                                  Wout, vc, counts, P0, P1, combo, bar);

        kernC2m<<<dim3(B_SZ), 256, 0, stream>>>(m1, Wout, vc, counts, P1);
        kernD<<<dim3(3), 256, 0, stream>>>(counts, out);
        return;
    }

    kernProbe<<<dim3(1), 64, 0, stream>>>(combo);
    if (use_wf)
        kernP<<<dim3(256), 256, 0, stream>>>(Wres, Wf, combo);

    kernI<<<dim3(NB / 256), 256, 0, stream>>>(x, Win, vr, sf0, sTa);
    for (int t = 1; t < T_STEPS; ++t) {
        const float* sfp = (t & 1) ? sf0 : sf1;
        float*       sfc = (t & 1) ? sf1 : sf0;
        float*       sTc = (t & 1) ? sTb : sTa;
        const float* sTp = (t & 1) ? sTa : sTb;
        if (use_wf)
            kernAB<true><<<dim3(320), 1024, 0, stream>>>(Wf, sfp, x, Win, vr, sfc, sTc, sTp,
                                                         Wout, vc, counts, combo, t);
        else
            kernAB<false><<<dim3(320), 1024, 0, stream>>>(Wres, sfp, x, Win, vr, sfc, sTc, sTp,
                                                          Wout, vc, counts, combo, t);
    }
    kernC<<<dim3(B_SZ), 256, 0, stream>>>(sTb, Wout, vc, counts);
    kernD<<<dim3(3), 256, 0, stream>>>(counts, out);
}

// Round 11
// 2427.861 us; speedup vs baseline: 1.8226x; 1.2687x over previous
//
#include <hip/hip_runtime.h>

#define N_NEUR 4096
#define B_SZ   64
#define T_STEPS 128
#define N_CLS  10

typedef double d4v __attribute__((ext_vector_type(4)));
typedef int    i4v __attribute__((ext_vector_type(4)));
typedef long   l2v __attribute__((ext_vector_type(2)));

// =====================================================================================
// i8 3-digit fixed-point path, per-step launches (hardware rendezvous).
// r10 post-mortem: persistent-kernel step time (23 us) is pinned by the SOFTWARE barrier
// latency chain, not compute (instruction cuts null) nor traffic (6x FETCH null).
// This round: one launch per step (kernel boundary = HW drain/coherence/sync), lean
// 256-block grid (no 320-block tail like r5's fallback), r10-verified body, plain
// loads/stores on the mask path, aR reloaded per step from L3-resident planes (issued
// early, overlaps mask copy).
// =====================================================================================

__device__ inline int korder2(int map, int khi, int e) {
    return map ? ((khi << 3) | e)
               : (((e >> 2) << 4) | (khi << 2) | (e & 3));
}

// ---------------- layout probe for i8 MFMA: combo[3] = am | bm<<1 | dmap<<2 ----------------
__global__ void kernProbe3(int* __restrict__ combo_out) {
    int l = threadIdx.x;
    int khi = l >> 4, c = l & 15;
    int best = -1;
    for (int cb = 0; cb < 8; ++cb) {
        int am = cb & 1, bm = (cb >> 1) & 1, dmap = (cb >> 2) & 1;
        unsigned long long au = 0, bu = 0;
        #pragma unroll
        for (int e = 0; e < 8; ++e) {
            int ka = korder2(am, khi, e);
            int kb = korder2(bm, khi, e);
            int aval = ((c * 5 + ka * 3) % 51) - 25;
            int bval = ((kb * 7 + c * 13) % 51) - 25;
            au |= (unsigned long long)(unsigned char)(char)aval << (8 * e);
            bu |= (unsigned long long)(unsigned char)(char)bval << (8 * e);
        }
        i4v d = {0, 0, 0, 0};
        d = __builtin_amdgcn_mfma_i32_16x16x32_i8((long)au, (long)bu, d, 0, 0, 0);
        bool ok = true;
        #pragma unroll
        for (int r = 0; r < 4; ++r) {
            int q = (l >> 4) * 4 + r;
            int di = dmap ? c : q;
            int dj = dmap ? q : c;
            int ref = 0;
            for (int k = 0; k < 32; ++k)
                ref += (((di * 5 + k * 3) % 51) - 25) * (((k * 7 + dj * 13) % 51) - 25);
            ok = ok && (d[r] == ref);
        }
        unsigned long long m = __ballot(ok);
        if (m == ~0ull && best < 0) best = cb;
    }
    if (l == 0) combo_out[3] = (best < 0) ? 0 : best;
}

// ---------------- global max|W| then scale exponent ----------------
__global__ __launch_bounds__(256) void kernS(const float* __restrict__ W, unsigned* __restrict__ mx) {
    unsigned m = 0;
    for (size_t i = (size_t)blockIdx.x * blockDim.x + threadIdx.x;
         i < (size_t)N_NEUR * N_NEUR; i += (size_t)gridDim.x * blockDim.x)
        m = max(m, __float_as_uint(fabsf(W[i])));
    for (int off = 32; off > 0; off >>= 1)
        m = max(m, (unsigned)__shfl_down((int)m, off, 64));
    if ((threadIdx.x & 63) == 0) atomicMax(mx, m);
}

__global__ void kernSc(const unsigned* __restrict__ mx, int* __restrict__ combo) {
    float m = __uint_as_float(*mx);
    int s = 26;
    if (m > 1e-30f) {
        s = (int)floorf(log2f(8.3e6f / m));
        while (ldexpf(m, s) > 8.3e6f) --s;
        while (ldexpf(m, s + 1) <= 8.3e6f) ++s;
    }
    combo[2] = s;
}

// ---------------- pack W into 3 i8 digit planes, A-fragment order (verified r4-r10) ----------------
__global__ __launch_bounds__(256) void kernP3(const float* __restrict__ W,
                                              char* __restrict__ Wf,
                                              const int* __restrict__ combo_p) {
    const int am = combo_p[3] & 1;
    const int sc = combo_p[2];
    const int nt = blockIdx.x;
    const int lane = threadIdx.x & 63, wv = threadIdx.x >> 6;
    const int khi = lane >> 4, ai = lane & 15;
    const float* wrow = W + (size_t)(nt * 16 + ai) * N_NEUR;
    for (int kt = wv; kt < 64; kt += 4) {
        unsigned long long p0[2] = {0, 0}, p1[2] = {0, 0}, p2[2] = {0, 0};
        #pragma unroll
        for (int half = 0; half < 2; ++half) {
            #pragma unroll
            for (int e = 0; e < 8; ++e) {
                int kk = kt * 64 + half * 32 + korder2(am, khi, e);
                float w = wrow[kk];
                int q = (int)rintf(ldexpf(w, sc));
                int b0 = (int)(char)(q & 255);  int r1 = (q - b0) >> 8;
                int b1 = (int)(char)(r1 & 255); int b2 = (r1 - b1) >> 8;
                p0[half] |= (unsigned long long)(unsigned char)(char)b0 << (8 * e);
                p1[half] |= (unsigned long long)(unsigned char)(char)b1 << (8 * e);
                p2[half] |= (unsigned long long)(unsigned char)(char)b2 << (8 * e);
            }
        }
        size_t base = (((size_t)nt * 64 + kt) * 3) * 1024 + (size_t)lane * 16;
        *(l2v*)(Wf + base)        = (l2v){(long)p0[0], (long)p0[1]};
        *(l2v*)(Wf + base + 1024) = (l2v){(long)p1[0], (long)p1[1]};
        *(l2v*)(Wf + base + 2048) = (l2v){(long)p2[0], (long)p2[1]};
    }
}

// ---------------- t=0 init: vr + spike bitmask ----------------
__global__ __launch_bounds__(256) void kernI3m(const float* __restrict__ x,
                                               const float* __restrict__ Win,
                                               double* __restrict__ vr,
                                               unsigned* __restrict__ m0) {
    int idx = blockIdx.x * 256 + threadIdx.x;
    int b = idx & 63, n = idx >> 6;
    double v = (double)x[b * T_STEPS] * (double)Win[n];
    bool sp = (v >= 1.0);
    vr[idx] = sp ? 0.0 : v;
    if (sp)
        atomicOr(&m0[b * 256 + (n >> 4)], 1u << (n & 15));
}

// bit(e) of byte8 -> byte e value {0,1}  (carry-free multiply spread, verified r7-r10)
__device__ __forceinline__ unsigned long long expand8(unsigned w, int khi, int bm) {
    unsigned byte8;
    if (bm) byte8 = (w >> (khi * 8)) & 0xFFu;
    else    byte8 = ((w >> (khi * 4)) & 0xFu) | (((w >> (16 + khi * 4)) & 0xFu) << 4);
    unsigned rev = __builtin_bitreverse32(byte8) >> 24;
    return (((unsigned long long)rev * 0x8040201008040201ULL)
            & 0x8080808080808080ULL) >> 7;
}

// ---------------- per-step kernel: 256 blocks x 1024 threads, HW sync between steps ----------------
__global__ __launch_bounds__(1024) void kernStep10(const char* __restrict__ Wf,
                                                   const unsigned* __restrict__ mp,
                                                   unsigned* __restrict__ mc,
                                                   const float* __restrict__ x,
                                                   const float* __restrict__ Win,
                                                   double* __restrict__ vr,
                                                   const float* __restrict__ Wout,
                                                   double* __restrict__ vc,
                                                   double* __restrict__ counts,
                                                   double* __restrict__ Pcur,
                                                   double* __restrict__ Pprev,
                                                   const int* __restrict__ combo_p,
                                                   int t) {
    __shared__ int2 lbufI[8][1024];           // 64 KB  exact i32-packed cross-wave reduce
    __shared__ unsigned Lm[128 * 65];         // 33 KB  combined mask words [jw][b] (pad 65)
    __shared__ unsigned char spk[1024];       //  1 KB  spike bits staging
    const int bid = blockIdx.x, tid = threadIdx.x;
    const int wave = tid >> 6, lane = tid & 63;
    const int comboI = combo_p[3];
    const int sc = combo_p[2];
    const int bm = (comboI >> 1) & 1, dmap = (comboI >> 2) & 1;
    const double inv = ldexp(1.0, -sc);
    const int khi = lane >> 4, c = lane & 15;

    // ---- issue resident-A loads EARLY (L3-resident planes; overlaps mask copy) ----
    l2v aR[12];
    {
        const char* ap = Wf + (((size_t)bid * 64 + (size_t)wave * 4) * 3) * 1024 + (size_t)lane * 16;
        #pragma unroll
        for (int f = 0; f < 12; ++f)
            aR[f] = *(const l2v*)(ap + f * 1024);
    }

    const int nn = bid * 16 + wave;
    const int bb = lane;
    const size_t gidx = (size_t)nn * 64 + bb;
    const int b2 = bid >> 2;
    const int mbase = (bid & 3) << 10;        // classifier m-range base

    // ---- bulk-copy spike mask -> LDS (plain loads; kernel boundary = acquire) ----
    {
        const unsigned long long* mp64 = (const unsigned long long*)mp;
        #pragma unroll
        for (int r = 0; r < 8; ++r) {
            int idx2 = r * 1024 + tid;                     // [b (idx2>>7)][jw (idx2&127)]
            unsigned long long v = mp64[idx2];
            int b = idx2 >> 7, jw = idx2 & 127;
            Lm[jw * 65 + b] = (unsigned)(v & 0xFFFFu) | ((unsigned)(v >> 32) << 16);
        }
    }
    double xin = (double)x[bb * T_STEPS + t] * (double)Win[nn];
    double vprev = vr[gidx];
    __syncthreads();                                       // S1: Lm ready

    // ---- GEMM: single pass, 4 b-tiles, bit-expanded B from LDS (verified r8/r10) ----
    i4v acc[4][3];
    #pragma unroll
    for (int i = 0; i < 4; ++i)
        #pragma unroll
        for (int s = 0; s < 3; ++s)
            acc[i][s] = (i4v){0, 0, 0, 0};
    #pragma unroll
    for (int kt = 0; kt < 4; ++kt) {
        int ktg = wave * 4 + kt;
        #pragma unroll
        for (int bl = 0; bl < 4; ++bl) {
            int bcol = bl * 16 + c;
            unsigned w0 = Lm[(ktg * 2 + 0) * 65 + bcol];
            unsigned w1 = Lm[(ktg * 2 + 1) * 65 + bcol];
            long lo = (long)expand8(w0, khi, bm);
            long hi = (long)expand8(w1, khi, bm);
            #pragma unroll
            for (int s = 0; s < 3; ++s) {
                acc[bl][s] = __builtin_amdgcn_mfma_i32_16x16x32_i8(aR[kt * 3 + s][0], lo, acc[bl][s], 0, 0, 0);
                acc[bl][s] = __builtin_amdgcn_mfma_i32_16x16x32_i8(aR[kt * 3 + s][1], hi, acc[bl][s], 0, 0, 0);
            }
        }
    }

    // ---- classifier: wave-per-class for s_{t-1}, batch b2, this block's 1024-m quarter ----
    double ctot = 0.0;
    if (wave < N_CLS) {
        const float* wrow = Wout + (size_t)wave * N_NEUR + mbase;
        double s = 0.0;
        #pragma unroll
        for (int j = 0; j < 16; ++j) {
            unsigned wd = Lm[((mbase >> 5) + j * 2 + (lane >> 5)) * 65 + b2];
            if ((wd >> (lane & 31)) & 1u)
                s += (double)wrow[j * 64 + lane];
        }
        for (int off = 32; off > 0; off >>= 1)
            s += __shfl_down(s, off, 64);
        ctot = s;                                          // valid on lane 0
    }

    // ---- exact i32-packed recombine + two-phase 16->8 cross-wave reduce (r8/r10) ----
    {
        int2 pk[4][4];
        int ix[4][4];
        #pragma unroll
        for (int bl = 0; bl < 4; ++bl) {
            #pragma unroll
            for (int r = 0; r < 4; ++r) {
                pk[bl][r].x = acc[bl][0][r] + acc[bl][1][r] * 256;   // 16-wave sum < 2^31
                pk[bl][r].y = acc[bl][2][r];
                int q = (lane >> 4) * 4 + r;
                int di = dmap ? (lane & 15) : q;
                int dj = dmap ? q : (lane & 15);
                ix[bl][r] = di * 64 + bl * 16 + dj;
            }
        }
        if (wave < 8) {
            #pragma unroll
            for (int bl = 0; bl < 4; ++bl)
                #pragma unroll
                for (int r = 0; r < 4; ++r)
                    lbufI[wave][ix[bl][r]] = pk[bl][r];
        }
        __syncthreads();                                   // S2
        if (wave >= 8) {
            #pragma unroll
            for (int bl = 0; bl < 4; ++bl)
                #pragma unroll
                for (int r = 0; r < 4; ++r) {
                    int2 tcur = lbufI[wave - 8][ix[bl][r]];
                    tcur.x += pk[bl][r].x;
                    tcur.y += pk[bl][r].y;
                    lbufI[wave - 8][ix[bl][r]] = tcur;
                }
        }
        __syncthreads();                                   // S3
    }

    // ---- reservoir LIF (one output per thread; single exact recombine) ----
    {
        int s01 = 0, s2 = 0;
        #pragma unroll
        for (int j = 0; j < 8; ++j) {
            int2 v2 = lbufI[j][tid];
            s01 += v2.x;
            s2  += v2.y;
        }
        double cur = inv * ((double)s01 + 65536.0 * (double)s2) + xin;
        double v = 0.9 * vprev + cur;
        bool sp = (v >= 1.0);
        vr[gidx] = sp ? 0.0 : v;
        spk[lane * 16 + wave] = sp ? 1 : 0;                // [b][n-local]
    }

    // classifier commit (4 blocks share Pcur[b2] entry -> atomic; visible next launch)
    if (wave < N_CLS && lane == 0)
        atomicAdd(&Pcur[b2 * N_CLS + wave], ctot);

    __syncthreads();                                       // S4: spk ready

    // ---- wave 0: mask store + classifier LIF for s_{t-2} from Pprev (prev launch) ----
    if (wave == 0) {
        unsigned v16 = 0;
        #pragma unroll
        for (int i = 0; i < 16; ++i) v16 |= (unsigned)spk[lane * 16 + i] << i;
        mc[lane * 256 + bid] = v16;
        if (lane < N_CLS && bid < B_SZ && t >= 2) {
            double pv = Pprev[bid * N_CLS + lane];
            double v = 0.9 * vc[bid * N_CLS + lane] + pv;
            bool sp = (v >= 1.0);
            vc[bid * N_CLS + lane] = sp ? 0.0 : v;
            if (sp) counts[bid * N_CLS + lane] += 1.0;
            Pprev[bid * N_CLS + lane] = 0.0;
        }
    }
}

// ---------------- epilogue: vc for s_126 (from P1) then s_127 (mask dot) ----------------
__global__ __launch_bounds__(256) void kernC2m(const unsigned* __restrict__ m1,
                                               const float* __restrict__ Wout,
                                               double* __restrict__ vc,
                                               double* __restrict__ counts,
                                               const double* __restrict__ Pp) {
    int b = blockIdx.x;
    int tid = threadIdx.x;
    if (tid < N_CLS) {
        double v = 0.9 * vc[b * N_CLS + tid] + Pp[b * N_CLS + tid];
        bool sp = (v >= 1.0);
        vc[b * N_CLS + tid] = sp ? 0.0 : v;
        if (sp) counts[b * N_CLS + tid] += 1.0;
    }
    double part[N_CLS];
    #pragma unroll
    for (int c = 0; c < N_CLS; ++c) part[c] = 0.0;
    for (int m = tid; m < N_NEUR; m += 256) {
        unsigned w = m1[b * 256 + (m >> 4)];
        if ((w >> (m & 15)) & 1u) {
            #pragma unroll
            for (int c = 0; c < N_CLS; ++c)
                part[c] += (double)Wout[c * N_NEUR + m];
        }
    }
    __shared__ double red[4][N_CLS];
    int lane = tid & 63, wv = tid >> 6;
    #pragma unroll
    for (int c = 0; c < N_CLS; ++c) {
        double v = part[c];
        for (int off = 32; off > 0; off >>= 1)
            v += __shfl_down(v, off, 64);
        if (lane == 0) red[wv][c] = v;
    }
    __syncthreads();
    if (tid < N_CLS) {
        double tot = red[0][tid] + red[1][tid] + red[2][tid] + red[3][tid];
        double v = 0.9 * vc[b * N_CLS + tid] + tot;
        bool sp = (v >= 1.0);
        vc[b * N_CLS + tid] = sp ? 0.0 : v;
        if (sp) counts[b * N_CLS + tid] += 1.0;
    }
}

__global__ void kernD(const double* __restrict__ counts, float* __restrict__ out) {
    int i = blockIdx.x * blockDim.x + threadIdx.x;
    if (i < B_SZ * N_CLS) out[i] = (float)counts[i];
}

// =====================================================================================
// f64 fallback path (verified) — used when ws too small for the i8 planes.
// =====================================================================================

__global__ void kernProbe(int* __restrict__ combo_out) {
    int l = threadIdx.x;
    int best = -1;
    for (int c = 0; c < 16; ++c) {
        int amap = c & 1, bmap = (c >> 1) & 1, dmap = (c >> 2) & 3;
        int ai = amap ? (l >> 2) : (l & 15);
        int ak = amap ? (l & 3)  : (l >> 4);
        int bk = bmap ? (l & 3)  : (l >> 4);
        int bj = bmap ? (l >> 2) : (l & 15);
        double a = (double)(ai * 4 + ak + 1);
        double b = (double)(bk * 16 + bj + 1);
        d4v d = {0.0, 0.0, 0.0, 0.0};
        d = __builtin_amdgcn_mfma_f64_16x16x4f64(a, b, d, 0, 0, 0);
        bool ok = true;
        #pragma unroll
        for (int r = 0; r < 4; ++r) {
            int di, dj;
            if      (dmap == 0) { di = 4 * (l >> 4) + r; dj = l & 15; }
            else if (dmap == 1) { di = l & 15; dj = 4 * (l >> 4) + r; }
            else if (dmap == 2) { di = (l >> 4) + 4 * r; dj = l & 15; }
            else                { di = l & 15; dj = (l >> 4) + 4 * r; }
            double ref = 0.0;
            for (int k = 0; k < 4; ++k)
                ref += (double)(di * 4 + k + 1) * (double)(k * 16 + dj + 1);
            ok = ok && (d[r] == ref);
        }
        unsigned long long m = __ballot(ok);
        if (m == ~0ull && best < 0) best = c;
    }
    if (l == 0) combo_out[0] = (best < 0) ? 0 : best;
}

__global__ __launch_bounds__(256) void kernP(const float* __restrict__ W,
                                             float* __restrict__ Wf,
                                             const int* __restrict__ combo_p) {
    const int combo = combo_p[0];
    const int amap = combo & 1;
    const int stripe = blockIdx.x;
    const int lane = threadIdx.x & 63;
    const int ai = amap ? (lane >> 2) : (lane & 15);
    const int ak = amap ? (lane & 3)  : (lane >> 4);
    const size_t nrow = (size_t)(stripe * 16 + ai) * N_NEUR;
    for (int q = threadIdx.x >> 6; q < 1024; q += 4)
        Wf[((size_t)stripe * 1024 + q) * 64 + lane] = W[nrow + 4 * q + ak];
}

__global__ __launch_bounds__(256) void kernI(const float* __restrict__ x,
                                             const float* __restrict__ Win,
                                             double* __restrict__ vr,
                                             float* __restrict__ sf,
                                             float* __restrict__ sT) {
    int idx = blockIdx.x * 256 + threadIdx.x;
    int b = idx & 63, n = idx >> 6;
    double v = (double)x[b * T_STEPS] * (double)Win[n];
    bool sp = (v >= 1.0);
    vr[idx] = sp ? 0.0 : v;
    float s = sp ? 1.0f : 0.0f;
    sT[idx] = s;
    sf[(size_t)(((n >> 2) * 4 + (b >> 4)) * 64) + (n & 3) * 16 + (b & 15)] = s;
}

template<bool USEWF>
__global__ __launch_bounds__(1024) void kernAB(const float* __restrict__ Wsrc,
                                               const float* __restrict__ sfp,
                                               const float* __restrict__ x,
                                               const float* __restrict__ Win,
                                               double* __restrict__ vr,
                                               float* __restrict__ sfc,
                                               float* __restrict__ sTc,
                                               const float* __restrict__ sTp,
                                               const float* __restrict__ Wout,
                                               double* __restrict__ vc,
                                               double* __restrict__ counts,
                                               const int* __restrict__ combo_p,
                                               int t) {
    __shared__ double lbuf[4][16 * 64];
    __shared__ double red[16][N_CLS];
    const int tid  = threadIdx.x;
    const int wave = tid >> 6, lane = tid & 63;

    if (blockIdx.x >= 256) {
        const int b = blockIdx.x - 256;
        double part[N_CLS];
        #pragma unroll
        for (int c = 0; c < N_CLS; ++c) part[c] = 0.0;
        for (int m = tid; m < N_NEUR; m += 1024) {
            double s = (double)sTp[(size_t)m * B_SZ + b];
            #pragma unroll
            for (int c = 0; c < N_CLS; ++c)
                part[c] = fma(s, (double)Wout[c * N_NEUR + m], part[c]);
        }
        #pragma unroll
        for (int c = 0; c < N_CLS; ++c) {
            double v = part[c];
            for (int off = 32; off > 0; off >>= 1)
                v += __shfl_down(v, off, 64);
            if (lane == 0) red[wave][c] = v;
        }
        __syncthreads();
        if (tid < N_CLS) {
            double tot = 0.0;
            #pragma unroll
            for (int wv = 0; wv < 16; ++wv) tot += red[wv][tid];
            double v = 0.9 * vc[b * N_CLS + tid] + tot;
            bool sp = (v >= 1.0);
            vc[b * N_CLS + tid] = sp ? 0.0 : v;
            if (sp) counts[b * N_CLS + tid] += 1.0;
        }
        return;
    }

    const int wb = wave & 3, wq = wave >> 2;
    const int gn0 = blockIdx.x * 16;
    const int combo = combo_p[0];
    const int amap = combo & 1, bmap = (combo >> 1) & 1, dmap = (combo >> 2) & 3;
    const int bk = bmap ? (lane & 3)  : (lane >> 4);
    const int bj = bmap ? (lane >> 2) : (lane & 15);

    d4v acc = {0.0, 0.0, 0.0, 0.0};
    const int q0 = wq * 256;
    const float* bp = sfp + (size_t)(q0 * 4 + wb) * 64 + bk * 16 + bj;

    if (USEWF) {
        const float* ap = Wsrc + ((size_t)blockIdx.x * 1024 + q0) * 64 + lane;
        for (int blk = 0; blk < 64; ++blk) {
            #pragma unroll
            for (int u = 0; u < 4; ++u) {
                double a  = (double)ap[u * 64];
                double bv = (double)bp[u * 256];
                acc = __builtin_amdgcn_mfma_f64_16x16x4f64(a, bv, acc, 0, 0, 0);
            }
            ap += 256;
            bp += 1024;
        }
    } else {
        const int ai = amap ? (lane >> 2) : (lane & 15);
        const int ak = amap ? (lane & 3)  : (lane >> 4);
        #pragma unroll 4
        for (int q = 0; q < 256; ++q) {
            double a  = (double)Wsrc[(size_t)(gn0 + ai) * N_NEUR + 4 * (q0 + q) + ak];
            double bv = (double)bp[(size_t)q * 256];
            acc = __builtin_amdgcn_mfma_f64_16x16x4f64(a, bv, acc, 0, 0, 0);
        }
    }

    {
        const int jb = 16 * wb;
        #pragma unroll
        for (int r = 0; r < 4; ++r) {
            int di, dj;
            if      (dmap == 0) { di = 4 * (lane >> 4) + r; dj = lane & 15; }
            else if (dmap == 1) { di = lane & 15; dj = 4 * (lane >> 4) + r; }
            else if (dmap == 2) { di = (lane >> 4) + 4 * r; dj = lane & 15; }
            else                { di = lane & 15; dj = (lane >> 4) + 4 * r; }
            lbuf[wq][di * 64 + jb + dj] = acc[r];
        }
    }
    __syncthreads();

    int nl = tid >> 6, b = tid & 63;
    int n = gn0 + nl;
    size_t gidx = (size_t)n * 64 + b;
    double cur = lbuf[0][tid] + lbuf[1][tid] + lbuf[2][tid] + lbuf[3][tid]
               + (double)x[b * T_STEPS + t] * (double)Win[n];
    double v = 0.9 * vr[gidx] + cur;
    bool sp = (v >= 1.0);
    vr[gidx] = sp ? 0.0 : v;
    float s = sp ? 1.0f : 0.0f;
    sTc[gidx] = s;
    sfc[(size_t)(((n >> 2) * 4 + (b >> 4)) * 64) + (n & 3) * 16 + (b & 15)] = s;
}

__global__ __launch_bounds__(256) void kernC(const float* __restrict__ sT,
                                             const float* __restrict__ Wout,
                                             double* __restrict__ vc,
                                             double* __restrict__ counts) {
    int b = blockIdx.x;
    int tid = threadIdx.x;
    double part[N_CLS];
    #pragma unroll
    for (int c = 0; c < N_CLS; ++c) part[c] = 0.0;
    for (int m = tid; m < N_NEUR; m += 256) {
        double s = (double)sT[(size_t)m * B_SZ + b];
        #pragma unroll
        for (int c = 0; c < N_CLS; ++c)
            part[c] = fma(s, (double)Wout[c * N_NEUR + m], part[c]);
    }
    __shared__ double red[4][N_CLS];
    int lane = tid & 63, wv = tid >> 6;
    #pragma unroll
    for (int c = 0; c < N_CLS; ++c) {
        double v = part[c];
        for (int off = 32; off > 0; off >>= 1)
            v += __shfl_down(v, off, 64);
        if (lane == 0) red[wv][c] = v;
    }
    __syncthreads();
    if (tid < N_CLS) {
        double tot = red[0][tid] + red[1][tid] + red[2][tid] + red[3][tid];
        double v = 0.9 * vc[b * N_CLS + tid] + tot;
        bool sp = (v >= 1.0);
        vc[b * N_CLS + tid] = sp ? 0.0 : v;
        if (sp) counts[b * N_CLS + tid] += 1.0;
    }
}

extern "C" void kernel_launch(void* const* d_in, const int* in_sizes, int n_in,
                              void* d_out, int out_size, void* d_ws, size_t ws_size,
                              hipStream_t stream) {
    const float* x    = (const float*)d_in[0];
    const float* Win  = (const float*)d_in[1];
    const float* Wres = (const float*)d_in[2];
    const float* Wout = (const float*)d_in[3];
    float* out = (float*)d_out;

    const size_t NB = (size_t)B_SZ * N_NEUR;
    char* w = (char*)d_ws;
    double* vr     = (double*)w;  w += NB * sizeof(double);
    float*  sTa    = (float*)w;   w += NB * sizeof(float);
    float*  sTb    = (float*)w;   w += NB * sizeof(float);
    float*  sf0    = (float*)w;   w += NB * sizeof(float);   // i8 path: mask m0 (64 KB used)
    float*  sf1    = (float*)w;   w += NB * sizeof(float);   // i8 path: mask m1
    double* vc     = (double*)w;  w += (size_t)B_SZ * N_CLS * sizeof(double);
    double* counts = (double*)w;  w += (size_t)B_SZ * N_CLS * sizeof(double);
    double* P0     = (double*)w;  w += (size_t)B_SZ * N_CLS * sizeof(double);
    double* P1     = (double*)w;  w += (size_t)B_SZ * N_CLS * sizeof(double);
    int*    combo  = (int*)w;     w += 256;
    unsigned* bar  = (unsigned*)w; w += 4096;                // unused this round
    float*  Wf     = (float*)w;   // f64 path: 64 MB packed W; i8 path: 48 MB digit planes

    size_t fixed = (size_t)(w - (char*)d_ws);
    bool use_i8 = (ws_size >= fixed + 3ull * N_NEUR * N_NEUR);
    bool use_wf = (ws_size >= fixed + (size_t)N_NEUR * N_NEUR * sizeof(float));

    hipMemsetAsync(vc, 0, 4ull * B_SZ * N_CLS * sizeof(double), stream);   // vc, counts, P0, P1
    hipMemsetAsync(combo, 0, 256, stream);

    if (use_i8) {
        char* Wfi = (char*)Wf;
        unsigned* m0 = (unsigned*)sf0;
        unsigned* m1 = (unsigned*)sf1;
        unsigned* mx = (unsigned*)(combo + 8);

        hipMemsetAsync(m0, 0, 64 * 1024, stream);
        hipMemsetAsync(m1, 0, 64 * 1024, stream);

        kernProbe3<<<dim3(1), 64, 0, stream>>>(combo);
        kernS<<<dim3(1024), 256, 0, stream>>>(Wres, mx);
        kernSc<<<dim3(1), 1, 0, stream>>>(mx, combo);
        kernP3<<<dim3(256), 256, 0, stream>>>(Wres, Wfi, combo);
        kernI3m<<<dim3(NB / 256), 256, 0, stream>>>(x, Win, vr, m0);

        for (int t = 1; t < T_STEPS; ++t) {
            const unsigned* mp = (t & 1) ? m0 : m1;
            unsigned*       mc = (t & 1) ? m1 : m0;
            double* Pcur  = (t & 1) ? P1 : P0;
            double* Pprev = (t & 1) ? P0 : P1;
            kernStep10<<<dim3(256), 1024, 0, stream>>>(Wfi, mp, mc, x, Win, vr,
                                                       Wout, vc, counts, Pcur, Pprev, combo, t);
        }

        kernC2m<<<dim3(B_SZ), 256, 0, stream>>>(m1, Wout, vc, counts, P1);
        kernD<<<dim3(3), 256, 0, stream>>>(counts, out);
        return;
    }

    kernProbe<<<dim3(1), 64, 0, stream>>>(combo);
    if (use_wf)
        kernP<<<dim3(256), 256, 0, stream>>>(Wres, Wf, combo);

    kernI<<<dim3(NB / 256), 256, 0, stream>>>(x, Win, vr, sf0, sTa);
    for (int t = 1; t < T_STEPS; ++t) {
        const float* sfp = (t & 1) ? sf0 : sf1;
        float*       sfc = (t & 1) ? sf1 : sf0;
        float*       sTc = (t & 1) ? sTb : sTa;
        const float* sTp = (t & 1) ? sTa : sTb;
        if (use_wf)
            kernAB<true><<<dim3(320), 1024, 0, stream>>>(Wf, sfp, x, Win, vr, sfc, sTc, sTp,
                                                         Wout, vc, counts, combo, t);
        else
            kernAB<false><<<dim3(320), 1024, 0, stream>>>(Wres, sfp, x, Win, vr, sfc, sTc, sTp,
                                                          Wout, vc, counts, combo, t);
    }
    kernC<<<dim3(B_SZ), 256, 0, stream>>>(sTb, Wout, vc, counts);
    kernD<<<dim3(3), 256, 0, stream>>>(counts, out);
}